// Round 5
// baseline (523.625 us; speedup 1.0000x reference)
//
#include <hip/hip_runtime.h>

#define N_NODES 100000
#define N_EDGES 600000
#define DIM 128
#define SCAN_B 1024
#define NCHUNK 98   // ceil(100000/1024)

typedef __attribute__((ext_vector_type(4))) float f32x4;
typedef __attribute__((ext_vector_type(8))) short bf16x8;
typedef __attribute__((ext_vector_type(4))) unsigned short u16x4;
typedef __attribute__((ext_vector_type(8))) unsigned short u16x8;

__device__ __forceinline__ unsigned short f2bf(float f) {
    union { float f; unsigned u; } cv; cv.f = f;
    unsigned r = (cv.u + 0x7FFFu + ((cv.u >> 16) & 1u)) >> 16;
    return (unsigned short)r;
}
__device__ __forceinline__ float bf2f(unsigned short v) {
    union { unsigned u; float f; } c; c.u = ((unsigned)v) << 16; return c.f;
}

// ---------------- setup: degree / scan / csr fill / weight pack ----------------

__global__ void k_degree(const int* __restrict__ src, int* __restrict__ degi) {
    int e = blockIdx.x * 256 + threadIdx.x;
    if (e < N_EDGES) atomicAdd(&degi[src[e]], 1);
}

__global__ void k_chunksum(const int* __restrict__ degi, int* __restrict__ bsum) {
    __shared__ int sm[SCAN_B];
    int i = blockIdx.x * SCAN_B + threadIdx.x;
    sm[threadIdx.x] = (i < N_NODES) ? degi[i] : 0;
    __syncthreads();
    for (int s = SCAN_B / 2; s > 0; s >>= 1) {
        if (threadIdx.x < (unsigned)s) sm[threadIdx.x] += sm[threadIdx.x + s];
        __syncthreads();
    }
    if (threadIdx.x == 0) bsum[blockIdx.x] = sm[0];
}

__global__ void k_scanb(int* __restrict__ bsum, int nb) {
    __shared__ int sm[128];
    int t = threadIdx.x;
    int v = (t < nb) ? bsum[t] : 0;
    sm[t] = v; __syncthreads();
    for (int s = 1; s < 128; s <<= 1) {
        int a = (t >= s) ? sm[t - s] : 0;
        __syncthreads();
        sm[t] += a;
        __syncthreads();
    }
    if (t < nb) bsum[t] = sm[t] - v;  // exclusive
}

__global__ void k_rowptr(const int* __restrict__ degi, const int* __restrict__ bsum,
                         int* __restrict__ rowptr, int* __restrict__ cnt,
                         float* __restrict__ inv0, float* __restrict__ inv1,
                         float* __restrict__ inv2) {
    __shared__ int sm[SCAN_B];
    int i = blockIdx.x * SCAN_B + threadIdx.x;
    int v = (i < N_NODES) ? degi[i] : 0;
    sm[threadIdx.x] = v; __syncthreads();
    for (int s = 1; s < SCAN_B; s <<= 1) {
        int a = (threadIdx.x >= (unsigned)s) ? sm[threadIdx.x - s] : 0;
        __syncthreads();
        sm[threadIdx.x] += a;
        __syncthreads();
    }
    if (i < N_NODES) {
        int excl = bsum[blockIdx.x] + sm[threadIdx.x] - v;
        rowptr[i] = excl;
        cnt[i] = excl;
        float d = (float)v;
        inv0[i] = (v > 0) ? 1.0f / d : 0.0f;
        inv1[i] = 1.0f / (d + 1.0f);
        inv2[i] = 1.0f / (d + 2.0f);
    }
}

__global__ void k_fill(const int* __restrict__ src, const int* __restrict__ dst,
                       int* __restrict__ cnt, int* __restrict__ col) {
    int e = blockIdx.x * 256 + threadIdx.x;
    if (e < N_EDGES) {
        int pos = atomicAdd(&cnt[src[e]], 1);
        col[pos] = dst[e];
    }
}

// Wpack[l][kb(8)][nt(16)][lane(64)][j(8)]  = W[k][n], k=kb*32+(lane>>4)*8+j, n=nt*16+(lane&15)
__global__ void k_pack(const float* __restrict__ G1, const float* __restrict__ G2,
                       const float* __restrict__ B1, const float* __restrict__ B2,
                       short* __restrict__ Wp) {
    int idx = blockIdx.x * 256 + threadIdx.x;  // 3*65536 = 196608 total
    int j = idx & 7, lane = (idx >> 3) & 63, nt = (idx >> 9) & 15, kb = (idx >> 13) & 7, l = idx >> 16;
    int k = kb * 32 + (lane >> 4) * 8 + j;
    int n = nt * 16 + (lane & 15);
    float v;
    if (n < 128) {
        v = (k < 128) ? G1[(l * 128 + n) * 128 + k] : G2[(l * 128 + n) * 128 + (k - 128)];
    } else {
        int n2 = n - 128;
        v = (k < 128) ? B1[(l * 128 + n2) * 128 + k] : B2[(l * 128 + n2) * 128 + (k - 128)];
    }
    Wp[idx] = (short)f2bf(v);
}

__global__ void k_xcast(const float* __restrict__ x, unsigned short* __restrict__ xb) {
    int i = (blockIdx.x * 256 + threadIdx.x) * 4;
    f32x4 v = *(const f32x4*)(x + i);
    unsigned short o0 = f2bf(v[0]), o1 = f2bf(v[1]), o2 = f2bf(v[2]), o3 = f2bf(v[3]);
    unsigned long long pk = (unsigned long long)o0 | ((unsigned long long)o1 << 16)
                          | ((unsigned long long)o2 << 32) | ((unsigned long long)o3 << 48);
    *(unsigned long long*)(xb + i) = pk;
}

// ---------------- gather: 4 rows per wave, 16B loads, shfl-broadcast cols ----------------
// lane = g*16 + c: sub-row g = lane>>4 handles its row; c indexes 8-bf16 (16B) chunks.

__device__ __forceinline__ void gather4(const u16x8* __restrict__ h8,
        const int* __restrict__ col, int start, int d, int lane, float* acc) {
    int c = lane & 15;
    int base = lane & 48;
    int dd = d < 16 ? d : 16;
    int idx = (c < dd) ? col[start + c] : 0;
    int dm = d;
    int tmx = __shfl_xor(dm, 16);
    dm = dm > tmx ? dm : tmx;
    tmx = __shfl_xor(dm, 32);
    dm = dm > tmx ? dm : tmx;          // wave-uniform max degree of the 4 rows
    int dmain = dm < 16 ? dm : 16;
    int e = 0;
    for (; e + 2 <= dmain; e += 2) {
        int c0 = __shfl(idx, base + e, 64);
        int c1 = __shfl(idx, base + e + 1, 64);
        if (e < d) {
            u16x8 v = h8[(size_t)c0 * 16 + c];
#pragma unroll
            for (int j = 0; j < 8; ++j) acc[j] += bf2f(v[j]);
        }
        if (e + 1 < d) {
            u16x8 v = h8[(size_t)c1 * 16 + c];
#pragma unroll
            for (int j = 0; j < 8; ++j) acc[j] += bf2f(v[j]);
        }
    }
    if (e < dmain) {
        int c0 = __shfl(idx, base + e, 64);
        if (e < d) {
            u16x8 v = h8[(size_t)c0 * 16 + c];
#pragma unroll
            for (int j = 0; j < 8; ++j) acc[j] += bf2f(v[j]);
        }
        ++e;
    }
    if (dm > 16) {  // cold path: deg > 16 (~handful of rows)
        for (; e < d; ++e) {
            int c0 = col[start + e];
            u16x8 v = h8[(size_t)c0 * 16 + c];
#pragma unroll
            for (int j = 0; j < 8; ++j) acc[j] += bf2f(v[j]);
        }
    }
}

// ---------------- device blocks: tail layer (gather+GEMM+update) and head hop ----------------

// Tail layer for 16 rows rb..rb+15. Phase 1: gather S into regs; stage S AND h (bf16)
// in LDS tiles; optionally emit head h1 = inv1*(S+x). Phase 2: Z = [h | inv0*S] @ Wl
// with A entirely from LDS, B from L1-hot Wp (each fragment loaded once per block:
// wave w owns nt pairs {2w,2w+1} and {2w+8,2w+9}). Epilogue in-register (z1/z2 same
// lane); h,S from LDS; h_new staged through LDS -> one coalesced 16B store per lane.
// m = h + gamma*R + beta - inv0*S;  h_new = inv2*(S + h + m)
// last: emb = 0.25*(x+t1+t2+t3) -> out rows with deg<=K only.
__device__ __forceinline__ void tail_block(
    int rb,
    unsigned short (*sH)[136], unsigned short (*sS)[136], unsigned short (*sO)[136],
    const unsigned short* __restrict__ hb,
    unsigned short* __restrict__ hA, int write_hA,
    unsigned short* __restrict__ hb_next,
    const unsigned short* __restrict__ xb, const unsigned short* __restrict__ t1b,
    float* __restrict__ outp,
    const float* __restrict__ Rl, const short* __restrict__ Wp,
    const float* __restrict__ inv0, const float* __restrict__ inv1,
    const float* __restrict__ inv2,
    const int* __restrict__ rowptr, const int* __restrict__ degi,
    const int* __restrict__ col, int last)
{
    int wave = threadIdx.x >> 6, lane = threadIdx.x & 63;

    // ---- phase 1: gather S for rows rb + wave*4 + g; stage S and h ----
    {
        int g = lane >> 4, c = lane & 15;
        int row = rb + wave * 4 + g;
        int start = rowptr[row], d = degi[row];
        float acc[8] = {0,0,0,0,0,0,0,0};
        gather4((const u16x8*)hb, col, start, d, lane, acc);
        u16x8 hv = ((const u16x8*)hb)[(size_t)row * 16 + c];
        u16x8 so;
#pragma unroll
        for (int j = 0; j < 8; ++j) so[j] = f2bf(acc[j]);
        *(u16x8*)&sS[wave * 4 + g][c * 8] = so;
        *(u16x8*)&sH[wave * 4 + g][c * 8] = hv;
        if (write_hA) {   // hop 0 only: head h1 = inv1*(S+x)
            float w1 = inv1[row];
            u16x8 ho;
#pragma unroll
            for (int j = 0; j < 8; ++j) ho[j] = f2bf(w1 * (acc[j] + bf2f(hv[j])));
            ((u16x8*)hA)[(size_t)row * 16 + c] = ho;
        }
    }
    __syncthreads();

    // ---- phase 2: GEMM for the block's 16 rows, A from LDS ----
    int q = lane >> 4, m = lane & 15;
    float w0 = inv0[rb + m];
    const short* wl = Wp + lane * 8;

    const f32x4 vz = {0.f, 0.f, 0.f, 0.f};
    f32x4 aA[2] = {vz, vz}, aB[2] = {vz, vz};

#pragma unroll
    for (int kb = 0; kb < 4; ++kb) {              // h-half of K
        bf16x8 ah = *(const bf16x8*)&sH[m][kb * 32 + q * 8];
#pragma unroll
        for (int j = 0; j < 2; ++j) {
            bf16x8 b1v = *(const bf16x8*)(wl + (kb * 16 + 2 * wave + j) * 512);
            bf16x8 b2v = *(const bf16x8*)(wl + (kb * 16 + 2 * wave + 8 + j) * 512);
            aA[j] = __builtin_amdgcn_mfma_f32_16x16x32_bf16(ah, b1v, aA[j], 0, 0, 0);
            aB[j] = __builtin_amdgcn_mfma_f32_16x16x32_bf16(ah, b2v, aB[j], 0, 0, 0);
        }
    }
#pragma unroll
    for (int kb = 0; kb < 4; ++kb) {              // inv0*S-half of K
        u16x8 sv = *(const u16x8*)&sS[m][kb * 32 + q * 8];
        bf16x8 as;
#pragma unroll
        for (int j = 0; j < 8; ++j) as[j] = (short)f2bf(w0 * bf2f(sv[j]));
#pragma unroll
        for (int j = 0; j < 2; ++j) {
            bf16x8 b1v = *(const bf16x8*)(wl + ((kb + 4) * 16 + 2 * wave + j) * 512);
            bf16x8 b2v = *(const bf16x8*)(wl + ((kb + 4) * 16 + 2 * wave + 8 + j) * 512);
            aA[j] = __builtin_amdgcn_mfma_f32_16x16x32_bf16(as, b1v, aA[j], 0, 0, 0);
            aB[j] = __builtin_amdgcn_mfma_f32_16x16x32_bf16(as, b2v, aB[j], 0, 0, 0);
        }
    }

    // ---- epilogue: C layout row = rb + q*4 + r, col = (2*wave+j)*16 + m ----
    float Rv[2];
#pragma unroll
    for (int j = 0; j < 2; ++j) Rv[j] = Rl[(2 * wave + j) * 16 + m];

#pragma unroll
    for (int r = 0; r < 4; ++r) {
        int gi = rb + q * 4 + r;
        float wi0 = inv0[gi], wi2 = inv2[gi];
        int dgi = degi[gi];
#pragma unroll
        for (int j = 0; j < 2; ++j) {
            int cc = (2 * wave + j) * 16 + m;
            float z1 = aA[j][r], z2 = aB[j][r];
            float h = bf2f(sH[q * 4 + r][cc]);
            float sva = bf2f(sS[q * 4 + r][cc]);
            float ga = (z1 > 0.f ? z1 : 0.2f * z1) + 1.0f;
            float be = (z2 > 0.f ? z2 : 0.2f * z2);
            float mm = h + ga * Rv[j] + be - wi0 * sva;
            float hn = wi2 * (sva + h + mm);
            if (!last) {
                sO[q * 4 + r][cc] = f2bf(hn);
            } else if (dgi <= 5) {
                float xv = bf2f(xb[(size_t)gi * DIM + cc]);
                float t1 = bf2f(t1b[(size_t)gi * DIM + cc]);
                outp[(size_t)gi * DIM + cc] = 0.25f * (xv + t1 + h + hn);
            }
        }
    }
    if (!last) {   // coalesced store of staged h_new
        __syncthreads();
        int g = lane >> 4, c = lane & 15;
        int row = rb + wave * 4 + g;
        ((u16x8*)hb_next)[(size_t)row * 16 + c] = *(u16x8*)&sO[wave * 4 + g][c * 8];
    }
}

// Head hop for 16 rows rb..rb+15: h_next = inv1*(S+h).
// final: emb = 0.25*(x+h1+h2+h3) -> out, ONLY rows with deg>K (tail-final owns deg<=K).
__device__ __forceinline__ void head_block(
    int rb,
    const unsigned short* __restrict__ hsrc, unsigned short* __restrict__ hnext,
    const unsigned short* __restrict__ xb, const unsigned short* __restrict__ h1b,
    float* __restrict__ outp, const float* __restrict__ inv1,
    const int* __restrict__ rowptr, const int* __restrict__ degi,
    const int* __restrict__ col, int final_hop)
{
    int wave = threadIdx.x >> 6, lane = threadIdx.x & 63;
    int g = lane >> 4, c = lane & 15;
    int row = rb + wave * 4 + g;
    int start = rowptr[row], d = degi[row];
    float acc[8] = {0,0,0,0,0,0,0,0};
    gather4((const u16x8*)hsrc, col, start, d, lane, acc);
    u16x8 hv = ((const u16x8*)hsrc)[(size_t)row * 16 + c];
    float w = inv1[row];
    float hn[8];
#pragma unroll
    for (int j = 0; j < 8; ++j) hn[j] = w * (acc[j] + bf2f(hv[j]));
    if (!final_hop) {
        u16x8 ho;
#pragma unroll
        for (int j = 0; j < 8; ++j) ho[j] = f2bf(hn[j]);
        ((u16x8*)hnext)[(size_t)row * 16 + c] = ho;
    } else if (d > 5) {
        u16x8 xv = ((const u16x8*)xb)[(size_t)row * 16 + c];
        u16x8 h1 = ((const u16x8*)h1b)[(size_t)row * 16 + c];
        f32x4 e0, e1;
#pragma unroll
        for (int j = 0; j < 4; ++j)
            e0[j] = 0.25f * (bf2f(xv[j]) + bf2f(h1[j]) + bf2f(hv[j]) + hn[j]);
#pragma unroll
        for (int j = 0; j < 4; ++j)
            e1[j] = 0.25f * (bf2f(xv[4 + j]) + bf2f(h1[4 + j]) + bf2f(hv[4 + j]) + hn[4 + j]);
        float* op = outp + (size_t)row * DIM + c * 8;
        *(f32x4*)op = e0;
        *(f32x4*)(op + 4) = e1;
    }
}

// ---------------- global kernels ----------------

// F0: shared hop 0 — gathers S(x) once, emits head h1 (hA) AND tail t1 via GEMM.
__global__ __launch_bounds__(256) void k_fused0(
    const unsigned short* __restrict__ xb, unsigned short* __restrict__ hA,
    unsigned short* __restrict__ tA, float* __restrict__ outp,
    const float* __restrict__ Rl, const short* __restrict__ Wp,
    const float* __restrict__ inv0, const float* __restrict__ inv1,
    const float* __restrict__ inv2,
    const int* __restrict__ rowptr, const int* __restrict__ degi,
    const int* __restrict__ col)
{
    __shared__ __align__(16) unsigned short sH[16][136], sS[16][136], sO[16][136];
    tail_block(blockIdx.x * 16, sH, sS, sO, xb, hA, 1, tA, xb, tA, outp,
               Rl, Wp, inv0, inv1, inv2, rowptr, degi, col, 0);
}

// Combined hop k: even blocks run the tail layer, odd blocks the head hop.
// The two chains are independent -> one launch overlaps two latency-bound passes.
__global__ __launch_bounds__(256) void k_combined(
    const unsigned short* __restrict__ tb, unsigned short* __restrict__ tb_next,
    const unsigned short* __restrict__ hsrc, unsigned short* __restrict__ hnext,
    const unsigned short* __restrict__ xb, const unsigned short* __restrict__ t1b,
    const unsigned short* __restrict__ h1b, float* __restrict__ outp,
    const float* __restrict__ Rl, const short* __restrict__ Wp,
    const float* __restrict__ inv0, const float* __restrict__ inv1,
    const float* __restrict__ inv2,
    const int* __restrict__ rowptr, const int* __restrict__ degi,
    const int* __restrict__ col, int lastfinal)
{
    __shared__ __align__(16) unsigned short sH[16][136], sS[16][136], sO[16][136];
    int bid = blockIdx.x;
    int rb = (bid >> 1) * 16;
    if (bid & 1) {
        head_block(rb, hsrc, hnext, xb, h1b, outp, inv1, rowptr, degi, col, lastfinal);
    } else {
        tail_block(rb, sH, sS, sO, tb, (unsigned short*)0, 0, tb_next, xb, t1b, outp,
                   Rl, Wp, inv0, inv1, inv2, rowptr, degi, col, lastfinal);
    }
}

// ---------------- launch ----------------

extern "C" void kernel_launch(void* const* d_in, const int* in_sizes, int n_in,
                              void* d_out, int out_size, void* d_ws, size_t ws_size,
                              hipStream_t stream) {
    const float* x  = (const float*)d_in[0];
    const float* G1 = (const float*)d_in[1];
    const float* G2 = (const float*)d_in[2];
    const float* B1 = (const float*)d_in[3];
    const float* B2 = (const float*)d_in[4];
    const float* R  = (const float*)d_in[5];
    const int* esrc = (const int*)d_in[6];
    const int* edst = (const int*)d_in[7];
    float* out = (float*)d_out;

    char* base = (char*)d_ws;
    size_t off = 0;
    auto alloc = [&](size_t b) -> void* {
        void* p = base + off;
        off = (off + b + 255) & ~(size_t)255;
        return p;
    };
    int* degi   = (int*)alloc(4 * N_NODES);
    int* rowptr = (int*)alloc(4 * N_NODES);
    int* cnt    = (int*)alloc(4 * N_NODES);
    int* bsum   = (int*)alloc(4 * 256);
    int* col    = (int*)alloc(4 * N_EDGES);
    float* inv0 = (float*)alloc(4 * N_NODES);
    float* inv1 = (float*)alloc(4 * N_NODES);
    float* inv2 = (float*)alloc(4 * N_NODES);
    short* Wp   = (short*)alloc(2 * 3 * 65536);
    unsigned short* xb = (unsigned short*)alloc(2ull * N_NODES * DIM);
    unsigned short* hA = (unsigned short*)alloc(2ull * N_NODES * DIM);  // head h1
    unsigned short* hB = (unsigned short*)alloc(2ull * N_NODES * DIM);  // head h2/h3 ping-pong
    unsigned short* tA = (unsigned short*)alloc(2ull * N_NODES * DIM);  // tail t1
    unsigned short* tB = (unsigned short*)alloc(2ull * N_NODES * DIM);  // tail t2

    hipMemsetAsync(degi, 0, 4 * N_NODES, stream);
    k_degree<<<(N_EDGES + 255) / 256, 256, 0, stream>>>(esrc, degi);
    k_chunksum<<<NCHUNK, SCAN_B, 0, stream>>>(degi, bsum);
    k_scanb<<<1, 128, 0, stream>>>(bsum, NCHUNK);
    k_rowptr<<<NCHUNK, SCAN_B, 0, stream>>>(degi, bsum, rowptr, cnt, inv0, inv1, inv2);
    k_fill<<<(N_EDGES + 255) / 256, 256, 0, stream>>>(esrc, edst, cnt, col);
    k_pack<<<768, 256, 0, stream>>>(G1, G2, B1, B2, Wp);
    k_xcast<<<12500, 256, 0, stream>>>(x, xb);

    // F0: shared hop 0 — gathers S(x) once, emits head h1 (hA) AND tail t1 (tA)
    k_fused0<<<6250, 256, 0, stream>>>(xb, hA, tA, out, R, Wp,
                                       inv0, inv1, inv2, rowptr, degi, col);

    // hop 1: tail layer 2 (tA->tB) + head hop (hA->hB), one launch
    k_combined<<<12500, 256, 0, stream>>>(tA, tB, hA, hB, xb, tA, hA, out,
                                          R + 128, Wp + 65536,
                                          inv0, inv1, inv2, rowptr, degi, col, 0);

    // hop 2 (final): tail layer 3 writes deg<=5 rows, head final writes deg>5 rows
    k_combined<<<12500, 256, 0, stream>>>(tB, tB, hB, hB, xb, tA, hA, out,
                                          R + 256, Wp + 131072,
                                          inv0, inv1, inv2, rowptr, degi, col, 1);
}

// Round 6
// 403.709 us; speedup vs baseline: 1.2970x; 1.2970x over previous
//
#include <hip/hip_runtime.h>

#define N_NODES 100000
#define N_EDGES 600000
#define DIM 128
#define SCAN_B 1024
#define NCHUNK 98   // ceil(100000/1024)

typedef __attribute__((ext_vector_type(4))) float f32x4;
typedef __attribute__((ext_vector_type(8))) short bf16x8;
typedef __attribute__((ext_vector_type(4))) unsigned short u16x4;
typedef __attribute__((ext_vector_type(8))) unsigned short u16x8;

__device__ __forceinline__ unsigned short f2bf(float f) {
    union { float f; unsigned u; } cv; cv.f = f;
    unsigned r = (cv.u + 0x7FFFu + ((cv.u >> 16) & 1u)) >> 16;
    return (unsigned short)r;
}
__device__ __forceinline__ float bf2f(unsigned short v) {
    union { unsigned u; float f; } c; c.u = ((unsigned)v) << 16; return c.f;
}

// ---------------- setup: degree / scan / csr fill / weight pack ----------------

__global__ void k_degree(const int* __restrict__ src, int* __restrict__ degi) {
    int e = blockIdx.x * 256 + threadIdx.x;
    if (e < N_EDGES) atomicAdd(&degi[src[e]], 1);
}

__global__ void k_chunksum(const int* __restrict__ degi, int* __restrict__ bsum) {
    __shared__ int sm[SCAN_B];
    int i = blockIdx.x * SCAN_B + threadIdx.x;
    sm[threadIdx.x] = (i < N_NODES) ? degi[i] : 0;
    __syncthreads();
    for (int s = SCAN_B / 2; s > 0; s >>= 1) {
        if (threadIdx.x < (unsigned)s) sm[threadIdx.x] += sm[threadIdx.x + s];
        __syncthreads();
    }
    if (threadIdx.x == 0) bsum[blockIdx.x] = sm[0];
}

__global__ void k_scanb(int* __restrict__ bsum, int nb) {
    __shared__ int sm[128];
    int t = threadIdx.x;
    int v = (t < nb) ? bsum[t] : 0;
    sm[t] = v; __syncthreads();
    for (int s = 1; s < 128; s <<= 1) {
        int a = (t >= s) ? sm[t - s] : 0;
        __syncthreads();
        sm[t] += a;
        __syncthreads();
    }
    if (t < nb) bsum[t] = sm[t] - v;  // exclusive
}

__global__ void k_rowptr(const int* __restrict__ degi, const int* __restrict__ bsum,
                         int* __restrict__ rowptr, int* __restrict__ cnt,
                         float* __restrict__ inv0, float* __restrict__ inv1,
                         float* __restrict__ inv2) {
    __shared__ int sm[SCAN_B];
    int i = blockIdx.x * SCAN_B + threadIdx.x;
    int v = (i < N_NODES) ? degi[i] : 0;
    sm[threadIdx.x] = v; __syncthreads();
    for (int s = 1; s < SCAN_B; s <<= 1) {
        int a = (threadIdx.x >= (unsigned)s) ? sm[threadIdx.x - s] : 0;
        __syncthreads();
        sm[threadIdx.x] += a;
        __syncthreads();
    }
    if (i < N_NODES) {
        int excl = bsum[blockIdx.x] + sm[threadIdx.x] - v;
        rowptr[i] = excl;
        cnt[i] = excl;
        float d = (float)v;
        inv0[i] = (v > 0) ? 1.0f / d : 0.0f;
        inv1[i] = 1.0f / (d + 1.0f);
        inv2[i] = 1.0f / (d + 2.0f);
    }
}

__global__ void k_fill(const int* __restrict__ src, const int* __restrict__ dst,
                       int* __restrict__ cnt, int* __restrict__ col) {
    int e = blockIdx.x * 256 + threadIdx.x;
    if (e < N_EDGES) {
        int pos = atomicAdd(&cnt[src[e]], 1);
        col[pos] = dst[e];
    }
}

// Wpack[l][kb(8)][nt(16)][lane(64)][j(8)]  = W[k][n], k=kb*32+(lane>>4)*8+j, n=nt*16+(lane&15)
__global__ void k_pack(const float* __restrict__ G1, const float* __restrict__ G2,
                       const float* __restrict__ B1, const float* __restrict__ B2,
                       short* __restrict__ Wp) {
    int idx = blockIdx.x * 256 + threadIdx.x;  // 3*65536 = 196608 total
    int j = idx & 7, lane = (idx >> 3) & 63, nt = (idx >> 9) & 15, kb = (idx >> 13) & 7, l = idx >> 16;
    int k = kb * 32 + (lane >> 4) * 8 + j;
    int n = nt * 16 + (lane & 15);
    float v;
    if (n < 128) {
        v = (k < 128) ? G1[(l * 128 + n) * 128 + k] : G2[(l * 128 + n) * 128 + (k - 128)];
    } else {
        int n2 = n - 128;
        v = (k < 128) ? B1[(l * 128 + n2) * 128 + k] : B2[(l * 128 + n2) * 128 + (k - 128)];
    }
    Wp[idx] = (short)f2bf(v);
}

__global__ void k_xcast(const float* __restrict__ x, unsigned short* __restrict__ xb) {
    int i = (blockIdx.x * 256 + threadIdx.x) * 4;
    f32x4 v = *(const f32x4*)(x + i);
    unsigned short o0 = f2bf(v[0]), o1 = f2bf(v[1]), o2 = f2bf(v[2]), o3 = f2bf(v[3]);
    unsigned long long pk = (unsigned long long)o0 | ((unsigned long long)o1 << 16)
                          | ((unsigned long long)o2 << 32) | ((unsigned long long)o3 << 48);
    *(unsigned long long*)(xb + i) = pk;
}

// ---------------- gather: 4 rows per wave, batched-issue loads for MLP ----------------
// lane = g*16 + c: sub-row g = lane>>4 handles its row; c indexes 8-bf16 (16B) chunks.
// All NE loads are issued unconditionally back-to-back (lanes past the row's degree
// read row 0 -- L1-hot, harmless), then accumulation runs predicated. This replaces
// the old 2-loads-per-iteration convoy (~5 serialized latency round trips per wave)
// with 1 batched round trip.

template <int NE>
__device__ __forceinline__ void gath_issue(const u16x8* __restrict__ h8,
        int idx, int base, int c, int d, float* acc) {
    u16x8 v[NE];
#pragma unroll
    for (int e = 0; e < NE; ++e) {
        int ce = __shfl(idx, base + e, 64);
        v[e] = h8[(size_t)ce * 16 + c];
    }
#pragma unroll
    for (int e = 0; e < NE; ++e) {
        if (e < d) {
#pragma unroll
            for (int j = 0; j < 8; ++j) acc[j] += bf2f(v[e][j]);
        }
    }
}

__device__ __forceinline__ void gather4(const u16x8* __restrict__ h8,
        const int* __restrict__ col, int start, int d, int lane, float* acc) {
    int c = lane & 15;
    int base = lane & 48;
    int dd = d < 16 ? d : 16;
    int idx = (c < dd) ? col[start + c] : 0;
    int dm = d;
    int tmx = __shfl_xor(dm, 16);
    dm = dm > tmx ? dm : tmx;
    tmx = __shfl_xor(dm, 32);
    dm = dm > tmx ? dm : tmx;          // wave-uniform max degree of the 4 rows
    if (dm <= 8) {
        gath_issue<8>(h8, idx, base, c, d, acc);
    } else {
        gath_issue<16>(h8, idx, base, c, d, acc);
        if (dm > 16) {  // cold path: deg > 16 (~handful of rows)
            for (int e = 16; e < d; ++e) {
                int c0 = col[start + e];
                u16x8 v = h8[(size_t)c0 * 16 + c];
#pragma unroll
                for (int j = 0; j < 8; ++j) acc[j] += bf2f(v[j]);
            }
        }
    }
}

// ---------------- device blocks: tail layer (gather+GEMM+update) and head hop ----------------

// Tail layer for 16 rows rb..rb+15. Phase 1: gather S into regs; stage S AND h (bf16)
// in LDS tiles; optionally emit head h1 = inv1*(S+x). Phase 2: Z = [h | inv0*S] @ Wl
// with A entirely from LDS, B from L1-hot Wp (each fragment loaded once per block:
// wave w owns nt pairs {2w,2w+1} and {2w+8,2w+9}). Epilogue in-register (z1/z2 same
// lane); h,S from LDS; h_new staged through LDS -> one coalesced 16B store per lane.
// m = h + gamma*R + beta - inv0*S;  h_new = inv2*(S + h + m)
// last: emb = 0.25*(x+t1+t2+t3) -> out rows with deg<=K only.
__device__ __forceinline__ void tail_block(
    int rb,
    unsigned short (*sH)[136], unsigned short (*sS)[136], unsigned short (*sO)[136],
    const unsigned short* __restrict__ hb,
    unsigned short* __restrict__ hA, int write_hA,
    unsigned short* __restrict__ hb_next,
    const unsigned short* __restrict__ xb, const unsigned short* __restrict__ t1b,
    float* __restrict__ outp,
    const float* __restrict__ Rl, const short* __restrict__ Wp,
    const float* __restrict__ inv0, const float* __restrict__ inv1,
    const float* __restrict__ inv2,
    const int* __restrict__ rowptr, const int* __restrict__ degi,
    const int* __restrict__ col, int last)
{
    int wave = threadIdx.x >> 6, lane = threadIdx.x & 63;

    // ---- phase 1: gather S for rows rb + wave*4 + g; stage S and h ----
    {
        int g = lane >> 4, c = lane & 15;
        int row = rb + wave * 4 + g;
        int start = rowptr[row], d = degi[row];
        u16x8 hv = ((const u16x8*)hb)[(size_t)row * 16 + c];  // issue own-row load first
        float acc[8] = {0,0,0,0,0,0,0,0};
        gather4((const u16x8*)hb, col, start, d, lane, acc);
        u16x8 so;
#pragma unroll
        for (int j = 0; j < 8; ++j) so[j] = f2bf(acc[j]);
        *(u16x8*)&sS[wave * 4 + g][c * 8] = so;
        *(u16x8*)&sH[wave * 4 + g][c * 8] = hv;
        if (write_hA) {   // hop 0 only: head h1 = inv1*(S+x)
            float w1 = inv1[row];
            u16x8 ho;
#pragma unroll
            for (int j = 0; j < 8; ++j) ho[j] = f2bf(w1 * (acc[j] + bf2f(hv[j])));
            ((u16x8*)hA)[(size_t)row * 16 + c] = ho;
        }
    }
    __syncthreads();

    // ---- phase 2: GEMM for the block's 16 rows, A from LDS ----
    int q = lane >> 4, m = lane & 15;
    float w0 = inv0[rb + m];
    const short* wl = Wp + lane * 8;

    const f32x4 vz = {0.f, 0.f, 0.f, 0.f};
    f32x4 aA[2] = {vz, vz}, aB[2] = {vz, vz};

#pragma unroll
    for (int kb = 0; kb < 4; ++kb) {              // h-half of K
        bf16x8 ah = *(const bf16x8*)&sH[m][kb * 32 + q * 8];
#pragma unroll
        for (int j = 0; j < 2; ++j) {
            bf16x8 b1v = *(const bf16x8*)(wl + (kb * 16 + 2 * wave + j) * 512);
            bf16x8 b2v = *(const bf16x8*)(wl + (kb * 16 + 2 * wave + 8 + j) * 512);
            aA[j] = __builtin_amdgcn_mfma_f32_16x16x32_bf16(ah, b1v, aA[j], 0, 0, 0);
            aB[j] = __builtin_amdgcn_mfma_f32_16x16x32_bf16(ah, b2v, aB[j], 0, 0, 0);
        }
    }
#pragma unroll
    for (int kb = 0; kb < 4; ++kb) {              // inv0*S-half of K
        u16x8 sv = *(const u16x8*)&sS[m][kb * 32 + q * 8];
        bf16x8 as;
#pragma unroll
        for (int j = 0; j < 8; ++j) as[j] = (short)f2bf(w0 * bf2f(sv[j]));
#pragma unroll
        for (int j = 0; j < 2; ++j) {
            bf16x8 b1v = *(const bf16x8*)(wl + ((kb + 4) * 16 + 2 * wave + j) * 512);
            bf16x8 b2v = *(const bf16x8*)(wl + ((kb + 4) * 16 + 2 * wave + 8 + j) * 512);
            aA[j] = __builtin_amdgcn_mfma_f32_16x16x32_bf16(as, b1v, aA[j], 0, 0, 0);
            aB[j] = __builtin_amdgcn_mfma_f32_16x16x32_bf16(as, b2v, aB[j], 0, 0, 0);
        }
    }

    // ---- epilogue: C layout row = rb + q*4 + r, col = (2*wave+j)*16 + m ----
    float Rv[2];
#pragma unroll
    for (int j = 0; j < 2; ++j) Rv[j] = Rl[(2 * wave + j) * 16 + m];

#pragma unroll
    for (int r = 0; r < 4; ++r) {
        int gi = rb + q * 4 + r;
        float wi0 = inv0[gi], wi2 = inv2[gi];
        int dgi = degi[gi];
#pragma unroll
        for (int j = 0; j < 2; ++j) {
            int cc = (2 * wave + j) * 16 + m;
            float z1 = aA[j][r], z2 = aB[j][r];
            float h = bf2f(sH[q * 4 + r][cc]);
            float sva = bf2f(sS[q * 4 + r][cc]);
            float ga = (z1 > 0.f ? z1 : 0.2f * z1) + 1.0f;
            float be = (z2 > 0.f ? z2 : 0.2f * z2);
            float mm = h + ga * Rv[j] + be - wi0 * sva;
            float hn = wi2 * (sva + h + mm);
            if (!last) {
                sO[q * 4 + r][cc] = f2bf(hn);
            } else if (dgi <= 5) {
                float xv = bf2f(xb[(size_t)gi * DIM + cc]);
                float t1 = bf2f(t1b[(size_t)gi * DIM + cc]);
                outp[(size_t)gi * DIM + cc] = 0.25f * (xv + t1 + h + hn);
            }
        }
    }
    if (!last) {   // coalesced store of staged h_new
        __syncthreads();
        int g = lane >> 4, c = lane & 15;
        int row = rb + wave * 4 + g;
        ((u16x8*)hb_next)[(size_t)row * 16 + c] = *(u16x8*)&sO[wave * 4 + g][c * 8];
    }
}

// Head hop for 16 rows rb..rb+15: h_next = inv1*(S+h).
// final: emb = 0.25*(x+h1+h2+h3) -> out, ONLY rows with deg>K (tail-final owns deg<=K).
__device__ __forceinline__ void head_block(
    int rb,
    const unsigned short* __restrict__ hsrc, unsigned short* __restrict__ hnext,
    const unsigned short* __restrict__ xb, const unsigned short* __restrict__ h1b,
    float* __restrict__ outp, const float* __restrict__ inv1,
    const int* __restrict__ rowptr, const int* __restrict__ degi,
    const int* __restrict__ col, int final_hop)
{
    int wave = threadIdx.x >> 6, lane = threadIdx.x & 63;
    int g = lane >> 4, c = lane & 15;
    int row = rb + wave * 4 + g;
    int start = rowptr[row], d = degi[row];
    u16x8 hv = ((const u16x8*)hsrc)[(size_t)row * 16 + c];
    float acc[8] = {0,0,0,0,0,0,0,0};
    gather4((const u16x8*)hsrc, col, start, d, lane, acc);
    float w = inv1[row];
    float hn[8];
#pragma unroll
    for (int j = 0; j < 8; ++j) hn[j] = w * (acc[j] + bf2f(hv[j]));
    if (!final_hop) {
        u16x8 ho;
#pragma unroll
        for (int j = 0; j < 8; ++j) ho[j] = f2bf(hn[j]);
        ((u16x8*)hnext)[(size_t)row * 16 + c] = ho;
    } else if (d > 5) {
        u16x8 xv = ((const u16x8*)xb)[(size_t)row * 16 + c];
        u16x8 h1 = ((const u16x8*)h1b)[(size_t)row * 16 + c];
        f32x4 e0, e1;
#pragma unroll
        for (int j = 0; j < 4; ++j)
            e0[j] = 0.25f * (bf2f(xv[j]) + bf2f(h1[j]) + bf2f(hv[j]) + hn[j]);
#pragma unroll
        for (int j = 0; j < 4; ++j)
            e1[j] = 0.25f * (bf2f(xv[4 + j]) + bf2f(h1[4 + j]) + bf2f(hv[4 + j]) + hn[4 + j]);
        float* op = outp + (size_t)row * DIM + c * 8;
        *(f32x4*)op = e0;
        *(f32x4*)(op + 4) = e1;
    }
}

// ---------------- global kernels ----------------

// F0: shared hop 0 — gathers S(x) once, emits head h1 (hA) AND tail t1 via GEMM.
__global__ __launch_bounds__(256, 4) void k_fused0(
    const unsigned short* __restrict__ xb, unsigned short* __restrict__ hA,
    unsigned short* __restrict__ tA, float* __restrict__ outp,
    const float* __restrict__ Rl, const short* __restrict__ Wp,
    const float* __restrict__ inv0, const float* __restrict__ inv1,
    const float* __restrict__ inv2,
    const int* __restrict__ rowptr, const int* __restrict__ degi,
    const int* __restrict__ col)
{
    __shared__ __align__(16) unsigned short sH[16][136], sS[16][136], sO[16][136];
    tail_block(blockIdx.x * 16, sH, sS, sO, xb, hA, 1, tA, xb, tA, outp,
               Rl, Wp, inv0, inv1, inv2, rowptr, degi, col, 0);
}

// Tail layers 2,3.
__global__ __launch_bounds__(256, 4) void k_tail(
    const unsigned short* __restrict__ tb, unsigned short* __restrict__ tb_next,
    const unsigned short* __restrict__ xb, const unsigned short* __restrict__ t1b,
    float* __restrict__ outp,
    const float* __restrict__ Rl, const short* __restrict__ Wp,
    const float* __restrict__ inv0, const float* __restrict__ inv1,
    const float* __restrict__ inv2,
    const int* __restrict__ rowptr, const int* __restrict__ degi,
    const int* __restrict__ col, int last)
{
    __shared__ __align__(16) unsigned short sH[16][136], sS[16][136], sO[16][136];
    tail_block(blockIdx.x * 16, sH, sS, sO, tb, (unsigned short*)0, 0, tb_next,
               xb, t1b, outp, Rl, Wp, inv0, inv1, inv2, rowptr, degi, col, last);
}

// Head hops 1,2.
__global__ __launch_bounds__(256, 4) void k_head(
    const unsigned short* __restrict__ hsrc, unsigned short* __restrict__ hnext,
    const unsigned short* __restrict__ xb, const unsigned short* __restrict__ h1b,
    float* __restrict__ outp, const float* __restrict__ inv1,
    const int* __restrict__ rowptr, const int* __restrict__ degi,
    const int* __restrict__ col, int final_hop)
{
    head_block(blockIdx.x * 16, hsrc, hnext, xb, h1b, outp, inv1,
               rowptr, degi, col, final_hop);
}

// ---------------- launch ----------------

extern "C" void kernel_launch(void* const* d_in, const int* in_sizes, int n_in,
                              void* d_out, int out_size, void* d_ws, size_t ws_size,
                              hipStream_t stream) {
    const float* x  = (const float*)d_in[0];
    const float* G1 = (const float*)d_in[1];
    const float* G2 = (const float*)d_in[2];
    const float* B1 = (const float*)d_in[3];
    const float* B2 = (const float*)d_in[4];
    const float* R  = (const float*)d_in[5];
    const int* esrc = (const int*)d_in[6];
    const int* edst = (const int*)d_in[7];
    float* out = (float*)d_out;

    char* base = (char*)d_ws;
    size_t off = 0;
    auto alloc = [&](size_t b) -> void* {
        void* p = base + off;
        off = (off + b + 255) & ~(size_t)255;
        return p;
    };
    int* degi   = (int*)alloc(4 * N_NODES);
    int* rowptr = (int*)alloc(4 * N_NODES);
    int* cnt    = (int*)alloc(4 * N_NODES);
    int* bsum   = (int*)alloc(4 * 256);
    int* col    = (int*)alloc(4 * N_EDGES);
    float* inv0 = (float*)alloc(4 * N_NODES);
    float* inv1 = (float*)alloc(4 * N_NODES);
    float* inv2 = (float*)alloc(4 * N_NODES);
    short* Wp   = (short*)alloc(2 * 3 * 65536);
    unsigned short* xb = (unsigned short*)alloc(2ull * N_NODES * DIM);
    unsigned short* hA = (unsigned short*)alloc(2ull * N_NODES * DIM);  // head h1
    unsigned short* hB = (unsigned short*)alloc(2ull * N_NODES * DIM);  // head h2/h3 ping-pong
    unsigned short* tA = (unsigned short*)alloc(2ull * N_NODES * DIM);  // tail t1
    unsigned short* tB = (unsigned short*)alloc(2ull * N_NODES * DIM);  // tail t2

    hipMemsetAsync(degi, 0, 4 * N_NODES, stream);
    k_degree<<<(N_EDGES + 255) / 256, 256, 0, stream>>>(esrc, degi);
    k_chunksum<<<NCHUNK, SCAN_B, 0, stream>>>(degi, bsum);
    k_scanb<<<1, 128, 0, stream>>>(bsum, NCHUNK);
    k_rowptr<<<NCHUNK, SCAN_B, 0, stream>>>(degi, bsum, rowptr, cnt, inv0, inv1, inv2);
    k_fill<<<(N_EDGES + 255) / 256, 256, 0, stream>>>(esrc, edst, cnt, col);
    k_pack<<<768, 256, 0, stream>>>(G1, G2, B1, B2, Wp);
    k_xcast<<<12500, 256, 0, stream>>>(x, xb);

    // F0: shared hop 0 — gathers S(x) once, emits head h1 (hA) AND tail t1 (tA)
    k_fused0<<<6250, 256, 0, stream>>>(xb, hA, tA, out, R, Wp,
                                       inv0, inv1, inv2, rowptr, degi, col);

    // head hops 1,2 (final writes deg>5 rows only)
    k_head<<<6250, 256, 0, stream>>>(hA, hB, xb, hA, out, inv1, rowptr, degi, col, 0);
    k_head<<<6250, 256, 0, stream>>>(hB, hB, xb, hA, out, inv1, rowptr, degi, col, 1);

    // tail layers 2,3 (final writes deg<=5 rows only)
    k_tail<<<6250, 256, 0, stream>>>(tA, tB, xb, tA, out, R + 128, Wp + 65536,
                                     inv0, inv1, inv2, rowptr, degi, col, 0);
    k_tail<<<6250, 256, 0, stream>>>(tB, tB, xb, tA, out, R + 256, Wp + 131072,
                                     inv0, inv1, inv2, rowptr, degi, col, 1);
}

// Round 7
// 397.164 us; speedup vs baseline: 1.3184x; 1.0165x over previous
//
#include <hip/hip_runtime.h>

#define N_NODES 100000
#define N_EDGES 600000
#define DIM 128
#define SCAN_B 1024
#define NCHUNK 98   // ceil(100000/1024)

typedef __attribute__((ext_vector_type(4))) float f32x4;
typedef __attribute__((ext_vector_type(8))) short bf16x8;
typedef __attribute__((ext_vector_type(4))) unsigned short u16x4;
typedef __attribute__((ext_vector_type(8))) unsigned short u16x8;

__device__ __forceinline__ unsigned short f2bf(float f) {
    union { float f; unsigned u; } cv; cv.f = f;
    unsigned r = (cv.u + 0x7FFFu + ((cv.u >> 16) & 1u)) >> 16;
    return (unsigned short)r;
}
__device__ __forceinline__ float bf2f(unsigned short v) {
    union { unsigned u; float f; } c; c.u = ((unsigned)v) << 16; return c.f;
}

// ---------------- setup: degree / scan / csr fill / weight pack ----------------

__global__ void k_degree(const int* __restrict__ src, int* __restrict__ degi) {
    int e = blockIdx.x * 256 + threadIdx.x;
    if (e < N_EDGES) atomicAdd(&degi[src[e]], 1);
}

__global__ void k_chunksum(const int* __restrict__ degi, int* __restrict__ bsum) {
    __shared__ int sm[SCAN_B];
    int i = blockIdx.x * SCAN_B + threadIdx.x;
    sm[threadIdx.x] = (i < N_NODES) ? degi[i] : 0;
    __syncthreads();
    for (int s = SCAN_B / 2; s > 0; s >>= 1) {
        if (threadIdx.x < (unsigned)s) sm[threadIdx.x] += sm[threadIdx.x + s];
        __syncthreads();
    }
    if (threadIdx.x == 0) bsum[blockIdx.x] = sm[0];
}

__global__ void k_scanb(int* __restrict__ bsum, int nb) {
    __shared__ int sm[128];
    int t = threadIdx.x;
    int v = (t < nb) ? bsum[t] : 0;
    sm[t] = v; __syncthreads();
    for (int s = 1; s < 128; s <<= 1) {
        int a = (t >= s) ? sm[t - s] : 0;
        __syncthreads();
        sm[t] += a;
        __syncthreads();
    }
    if (t < nb) bsum[t] = sm[t] - v;  // exclusive
}

__global__ void k_rowptr(const int* __restrict__ degi, const int* __restrict__ bsum,
                         int* __restrict__ rowptr, int* __restrict__ cnt,
                         float* __restrict__ inv0, float* __restrict__ inv1,
                         float* __restrict__ inv2) {
    __shared__ int sm[SCAN_B];
    int i = blockIdx.x * SCAN_B + threadIdx.x;
    int v = (i < N_NODES) ? degi[i] : 0;
    sm[threadIdx.x] = v; __syncthreads();
    for (int s = 1; s < SCAN_B; s <<= 1) {
        int a = (threadIdx.x >= (unsigned)s) ? sm[threadIdx.x - s] : 0;
        __syncthreads();
        sm[threadIdx.x] += a;
        __syncthreads();
    }
    if (i < N_NODES) {
        int excl = bsum[blockIdx.x] + sm[threadIdx.x] - v;
        rowptr[i] = excl;
        cnt[i] = excl;
        float d = (float)v;
        inv0[i] = (v > 0) ? 1.0f / d : 0.0f;
        inv1[i] = 1.0f / (d + 1.0f);
        inv2[i] = 1.0f / (d + 2.0f);
    }
}

__global__ void k_fill(const int* __restrict__ src, const int* __restrict__ dst,
                       int* __restrict__ cnt, int* __restrict__ col) {
    int e = blockIdx.x * 256 + threadIdx.x;
    if (e < N_EDGES) {
        int pos = atomicAdd(&cnt[src[e]], 1);
        col[pos] = dst[e];
    }
}

// Wpack[l][kb(8)][nt(16)][lane(64)][j(8)]  = W[k][n], k=kb*32+(lane>>4)*8+j, n=nt*16+(lane&15)
__global__ void k_pack(const float* __restrict__ G1, const float* __restrict__ G2,
                       const float* __restrict__ B1, const float* __restrict__ B2,
                       short* __restrict__ Wp) {
    int idx = blockIdx.x * 256 + threadIdx.x;  // 3*65536 = 196608 total
    int j = idx & 7, lane = (idx >> 3) & 63, nt = (idx >> 9) & 15, kb = (idx >> 13) & 7, l = idx >> 16;
    int k = kb * 32 + (lane >> 4) * 8 + j;
    int n = nt * 16 + (lane & 15);
    float v;
    if (n < 128) {
        v = (k < 128) ? G1[(l * 128 + n) * 128 + k] : G2[(l * 128 + n) * 128 + (k - 128)];
    } else {
        int n2 = n - 128;
        v = (k < 128) ? B1[(l * 128 + n2) * 128 + k] : B2[(l * 128 + n2) * 128 + (k - 128)];
    }
    Wp[idx] = (short)f2bf(v);
}

__global__ void k_xcast(const float* __restrict__ x, unsigned short* __restrict__ xb) {
    int i = (blockIdx.x * 256 + threadIdx.x) * 4;
    f32x4 v = *(const f32x4*)(x + i);
    unsigned short o0 = f2bf(v[0]), o1 = f2bf(v[1]), o2 = f2bf(v[2]), o3 = f2bf(v[3]);
    unsigned long long pk = (unsigned long long)o0 | ((unsigned long long)o1 << 16)
                          | ((unsigned long long)o2 << 32) | ((unsigned long long)o3 << 48);
    *(unsigned long long*)(xb + i) = pk;
}

// ---------------- gather: 4 rows per wave, batched-issue loads for MLP ----------------
// lane = g*16 + c: sub-row g = lane>>4 handles its row; c indexes 8-bf16 (16B) chunks.

template <int NE>
__device__ __forceinline__ void gath_issue(const u16x8* __restrict__ h8,
        int idx, int base, int c, int d, float* acc) {
    u16x8 v[NE];
#pragma unroll
    for (int e = 0; e < NE; ++e) {
        int ce = __shfl(idx, base + e, 64);
        v[e] = h8[(size_t)ce * 16 + c];
    }
#pragma unroll
    for (int e = 0; e < NE; ++e) {
        if (e < d) {
#pragma unroll
            for (int j = 0; j < 8; ++j) acc[j] += bf2f(v[e][j]);
        }
    }
}

__device__ __forceinline__ void gather4(const u16x8* __restrict__ h8,
        const int* __restrict__ col, int start, int d, int lane, float* acc) {
    int c = lane & 15;
    int base = lane & 48;
    int dd = d < 16 ? d : 16;
    int idx = (c < dd) ? col[start + c] : 0;
    int dm = d;
    int tmx = __shfl_xor(dm, 16);
    dm = dm > tmx ? dm : tmx;
    tmx = __shfl_xor(dm, 32);
    dm = dm > tmx ? dm : tmx;          // wave-uniform max degree of the 4 rows
    if (dm <= 8) {
        gath_issue<8>(h8, idx, base, c, d, acc);
    } else {
        gath_issue<16>(h8, idx, base, c, d, acc);
        if (dm > 16) {  // cold path: deg > 16 (~handful of rows)
            for (int e = 16; e < d; ++e) {
                int c0 = col[start + e];
                u16x8 v = h8[(size_t)c0 * 16 + c];
#pragma unroll
                for (int j = 0; j < 8; ++j) acc[j] += bf2f(v[j]);
            }
        }
    }
}

// Dual-array batched gather: same indices, two feature arrays (tail state + head state).
// Interleaved issue -> 2*NE independent loads in one latency round trip.
template <int NE>
__device__ __forceinline__ void gath_issue2(const u16x8* __restrict__ hT,
        const u16x8* __restrict__ hH,
        int idx, int base, int c, int d, int e0, float* accT, float* accH) {
    u16x8 vT[NE], vH[NE];
#pragma unroll
    for (int e = 0; e < NE; ++e) {
        int ce = __shfl(idx, base + e0 + e, 64);
        vT[e] = hT[(size_t)ce * 16 + c];
        vH[e] = hH[(size_t)ce * 16 + c];
    }
#pragma unroll
    for (int e = 0; e < NE; ++e) {
        if (e0 + e < d) {
#pragma unroll
            for (int j = 0; j < 8; ++j) {
                accT[j] += bf2f(vT[e][j]);
                accH[j] += bf2f(vH[e][j]);
            }
        }
    }
}

__device__ __forceinline__ void gather4_dual(const u16x8* __restrict__ hT,
        const u16x8* __restrict__ hH,
        const int* __restrict__ col, int start, int d, int lane,
        float* accT, float* accH) {
    int c = lane & 15;
    int base = lane & 48;
    int dd = d < 16 ? d : 16;
    int idx = (c < dd) ? col[start + c] : 0;
    int dm = d;
    int tmx = __shfl_xor(dm, 16);
    dm = dm > tmx ? dm : tmx;
    tmx = __shfl_xor(dm, 32);
    dm = dm > tmx ? dm : tmx;
    if (dm <= 8) {
        gath_issue2<8>(hT, hH, idx, base, c, d, 0, accT, accH);
    } else {
        gath_issue2<8>(hT, hH, idx, base, c, d, 0, accT, accH);
        gath_issue2<8>(hT, hH, idx, base, c, d, 8, accT, accH);
        if (dm > 16) {  // cold path
            for (int e = 16; e < d; ++e) {
                int c0 = col[start + e];
                u16x8 vT = hT[(size_t)c0 * 16 + c];
                u16x8 vH = hH[(size_t)c0 * 16 + c];
#pragma unroll
                for (int j = 0; j < 8; ++j) {
                    accT[j] += bf2f(vT[j]);
                    accH[j] += bf2f(vH[j]);
                }
            }
        }
    }
}

// ---------------- tail GEMM phase (shared by F0 and k_hop) ----------------
// Z = [h | inv0*S] @ Wl (256 cols), A from LDS (sH = h tile, sS = raw S tile),
// B from L1-hot Wp: wave w owns nt pairs {2w,2w+1} and {2w+8,2w+9}. Epilogue
// in-register (z1/z2 same lane); h_new staged through sO -> coalesced store.
// m = h + gamma*R + beta - inv0*S;  h_new = inv2*(S + h + m)
// last: emb = 0.25*(x+t1+t2+t3) -> out rows with deg<=5 only.
__device__ __forceinline__ void tail_gemm(
    int rb,
    unsigned short (*sH)[136], unsigned short (*sS)[136], unsigned short (*sO)[136],
    unsigned short* __restrict__ hb_next,
    const unsigned short* __restrict__ xb, const unsigned short* __restrict__ t1b,
    float* __restrict__ outp,
    const float* __restrict__ Rl, const short* __restrict__ Wp,
    const float* __restrict__ inv0, const float* __restrict__ inv2,
    const int* __restrict__ degi, int last)
{
    int wave = threadIdx.x >> 6, lane = threadIdx.x & 63;
    int q = lane >> 4, m = lane & 15;
    float w0 = inv0[rb + m];
    const short* wl = Wp + lane * 8;

    const f32x4 vz = {0.f, 0.f, 0.f, 0.f};
    f32x4 aA[2] = {vz, vz}, aB[2] = {vz, vz};

#pragma unroll
    for (int kb = 0; kb < 4; ++kb) {              // h-half of K
        bf16x8 ah = *(const bf16x8*)&sH[m][kb * 32 + q * 8];
#pragma unroll
        for (int j = 0; j < 2; ++j) {
            bf16x8 b1v = *(const bf16x8*)(wl + (kb * 16 + 2 * wave + j) * 512);
            bf16x8 b2v = *(const bf16x8*)(wl + (kb * 16 + 2 * wave + 8 + j) * 512);
            aA[j] = __builtin_amdgcn_mfma_f32_16x16x32_bf16(ah, b1v, aA[j], 0, 0, 0);
            aB[j] = __builtin_amdgcn_mfma_f32_16x16x32_bf16(ah, b2v, aB[j], 0, 0, 0);
        }
    }
#pragma unroll
    for (int kb = 0; kb < 4; ++kb) {              // inv0*S-half of K
        u16x8 sv = *(const u16x8*)&sS[m][kb * 32 + q * 8];
        bf16x8 as;
#pragma unroll
        for (int j = 0; j < 8; ++j) as[j] = (short)f2bf(w0 * bf2f(sv[j]));
#pragma unroll
        for (int j = 0; j < 2; ++j) {
            bf16x8 b1v = *(const bf16x8*)(wl + ((kb + 4) * 16 + 2 * wave + j) * 512);
            bf16x8 b2v = *(const bf16x8*)(wl + ((kb + 4) * 16 + 2 * wave + 8 + j) * 512);
            aA[j] = __builtin_amdgcn_mfma_f32_16x16x32_bf16(as, b1v, aA[j], 0, 0, 0);
            aB[j] = __builtin_amdgcn_mfma_f32_16x16x32_bf16(as, b2v, aB[j], 0, 0, 0);
        }
    }

    // ---- epilogue: C layout row = rb + q*4 + r, col = (2*wave+j)*16 + m ----
    float Rv[2];
#pragma unroll
    for (int j = 0; j < 2; ++j) Rv[j] = Rl[(2 * wave + j) * 16 + m];

#pragma unroll
    for (int r = 0; r < 4; ++r) {
        int gi = rb + q * 4 + r;
        float wi0 = inv0[gi], wi2 = inv2[gi];
        int dgi = degi[gi];
#pragma unroll
        for (int j = 0; j < 2; ++j) {
            int cc = (2 * wave + j) * 16 + m;
            float z1 = aA[j][r], z2 = aB[j][r];
            float h = bf2f(sH[q * 4 + r][cc]);
            float sva = bf2f(sS[q * 4 + r][cc]);
            float ga = (z1 > 0.f ? z1 : 0.2f * z1) + 1.0f;
            float be = (z2 > 0.f ? z2 : 0.2f * z2);
            float mm = h + ga * Rv[j] + be - wi0 * sva;
            float hn = wi2 * (sva + h + mm);
            if (!last) {
                sO[q * 4 + r][cc] = f2bf(hn);
            } else if (dgi <= 5) {
                float xv = bf2f(xb[(size_t)gi * DIM + cc]);
                float t1 = bf2f(t1b[(size_t)gi * DIM + cc]);
                outp[(size_t)gi * DIM + cc] = 0.25f * (xv + t1 + h + hn);
            }
        }
    }
    if (!last) {   // coalesced store of staged h_new
        __syncthreads();
        int g = lane >> 4, c = lane & 15;
        int row = rb + wave * 4 + g;
        ((u16x8*)hb_next)[(size_t)row * 16 + c] = *(u16x8*)&sO[wave * 4 + g][c * 8];
    }
}

// ---------------- global kernels ----------------

// F0: shared hop 0 — single gather of S(x); emits head h1 (hA) AND tail t1 via GEMM.
__global__ __launch_bounds__(256, 4) void k_fused0(
    const unsigned short* __restrict__ xb, unsigned short* __restrict__ hA,
    unsigned short* __restrict__ tA, float* __restrict__ outp,
    const float* __restrict__ Rl, const short* __restrict__ Wp,
    const float* __restrict__ inv0, const float* __restrict__ inv1,
    const float* __restrict__ inv2,
    const int* __restrict__ rowptr, const int* __restrict__ degi,
    const int* __restrict__ col)
{
    __shared__ __align__(16) unsigned short sH[16][136], sS[16][136], sO[16][136];
    int rb = blockIdx.x * 16;
    int wave = threadIdx.x >> 6, lane = threadIdx.x & 63;
    {
        int g = lane >> 4, c = lane & 15;
        int row = rb + wave * 4 + g;
        int start = rowptr[row], d = degi[row];
        u16x8 hv = ((const u16x8*)xb)[(size_t)row * 16 + c];
        float acc[8] = {0,0,0,0,0,0,0,0};
        gather4((const u16x8*)xb, col, start, d, lane, acc);
        u16x8 so;
#pragma unroll
        for (int j = 0; j < 8; ++j) so[j] = f2bf(acc[j]);
        *(u16x8*)&sS[wave * 4 + g][c * 8] = so;
        *(u16x8*)&sH[wave * 4 + g][c * 8] = hv;
        float w1 = inv1[row];   // head h1 = inv1*(S+x)
        u16x8 ho;
#pragma unroll
        for (int j = 0; j < 8; ++j) ho[j] = f2bf(w1 * (acc[j] + bf2f(hv[j])));
        ((u16x8*)hA)[(size_t)row * 16 + c] = ho;
    }
    __syncthreads();
    tail_gemm(rb, sH, sS, sO, tA, xb, tA, outp, Rl, Wp, inv0, inv2, degi, 0);
}

// Fused hop k: ONE dual gather over (tail state, head state) with shared indices.
// Head update written directly; tail S/h staged to LDS -> GEMM + epilogue.
// final (last=1): head writes emb rows deg>5, tail epilogue writes rows deg<=5.
__global__ __launch_bounds__(256, 4) void k_hop(
    const unsigned short* __restrict__ tb, unsigned short* __restrict__ tb_next,
    const unsigned short* __restrict__ hb, unsigned short* __restrict__ hb_next,
    const unsigned short* __restrict__ xb, const unsigned short* __restrict__ t1b,
    const unsigned short* __restrict__ h1b, float* __restrict__ outp,
    const float* __restrict__ Rl, const short* __restrict__ Wp,
    const float* __restrict__ inv0, const float* __restrict__ inv1,
    const float* __restrict__ inv2,
    const int* __restrict__ rowptr, const int* __restrict__ degi,
    const int* __restrict__ col, int last)
{
    __shared__ __align__(16) unsigned short sH[16][136], sS[16][136], sO[16][136];
    int rb = blockIdx.x * 16;
    int wave = threadIdx.x >> 6, lane = threadIdx.x & 63;

    // ---- phase 1: dual gather for rows rb + wave*4 + g ----
    {
        int g = lane >> 4, c = lane & 15;
        int row = rb + wave * 4 + g;
        int start = rowptr[row], d = degi[row];
        u16x8 tv = ((const u16x8*)tb)[(size_t)row * 16 + c];
        u16x8 hv = ((const u16x8*)hb)[(size_t)row * 16 + c];
        float accT[8] = {0,0,0,0,0,0,0,0};
        float accH[8] = {0,0,0,0,0,0,0,0};
        gather4_dual((const u16x8*)tb, (const u16x8*)hb, col, start, d, lane, accT, accH);

        // tail staging
        u16x8 so;
#pragma unroll
        for (int j = 0; j < 8; ++j) so[j] = f2bf(accT[j]);
        *(u16x8*)&sS[wave * 4 + g][c * 8] = so;
        *(u16x8*)&sH[wave * 4 + g][c * 8] = tv;

        // head update: h_next = inv1*(S_h + h)
        float w1 = inv1[row];
        if (!last) {
            u16x8 ho;
#pragma unroll
            for (int j = 0; j < 8; ++j) ho[j] = f2bf(w1 * (accH[j] + bf2f(hv[j])));
            ((u16x8*)hb_next)[(size_t)row * 16 + c] = ho;
        } else if (d > 5) {   // head final: emb = 0.25*(x+h1+h2+h3), h2=hv, h3=w1*(accH+hv)
            u16x8 xv = ((const u16x8*)xb)[(size_t)row * 16 + c];
            u16x8 h1 = ((const u16x8*)h1b)[(size_t)row * 16 + c];
            f32x4 e0, e1;
#pragma unroll
            for (int j = 0; j < 4; ++j) {
                float h2 = bf2f(hv[j]);
                e0[j] = 0.25f * (bf2f(xv[j]) + bf2f(h1[j]) + h2 + w1 * (accH[j] + h2));
            }
#pragma unroll
            for (int j = 0; j < 4; ++j) {
                float h2 = bf2f(hv[4 + j]);
                e1[j] = 0.25f * (bf2f(xv[4 + j]) + bf2f(h1[4 + j]) + h2 + w1 * (accH[4 + j] + h2));
            }
            float* op = outp + (size_t)row * DIM + c * 8;
            *(f32x4*)op = e0;
            *(f32x4*)(op + 4) = e1;
        }
    }
    __syncthreads();

    // ---- phase 2: tail GEMM + epilogue ----
    tail_gemm(rb, sH, sS, sO, tb_next, xb, t1b, outp, Rl, Wp, inv0, inv2, degi, last);
}

// ---------------- launch ----------------

extern "C" void kernel_launch(void* const* d_in, const int* in_sizes, int n_in,
                              void* d_out, int out_size, void* d_ws, size_t ws_size,
                              hipStream_t stream) {
    const float* x  = (const float*)d_in[0];
    const float* G1 = (const float*)d_in[1];
    const float* G2 = (const float*)d_in[2];
    const float* B1 = (const float*)d_in[3];
    const float* B2 = (const float*)d_in[4];
    const float* R  = (const float*)d_in[5];
    const int* esrc = (const int*)d_in[6];
    const int* edst = (const int*)d_in[7];
    float* out = (float*)d_out;

    char* base = (char*)d_ws;
    size_t off = 0;
    auto alloc = [&](size_t b) -> void* {
        void* p = base + off;
        off = (off + b + 255) & ~(size_t)255;
        return p;
    };
    int* degi   = (int*)alloc(4 * N_NODES);
    int* rowptr = (int*)alloc(4 * N_NODES);
    int* cnt    = (int*)alloc(4 * N_NODES);
    int* bsum   = (int*)alloc(4 * 256);
    int* col    = (int*)alloc(4 * N_EDGES);
    float* inv0 = (float*)alloc(4 * N_NODES);
    float* inv1 = (float*)alloc(4 * N_NODES);
    float* inv2 = (float*)alloc(4 * N_NODES);
    short* Wp   = (short*)alloc(2 * 3 * 65536);
    unsigned short* xb = (unsigned short*)alloc(2ull * N_NODES * DIM);
    unsigned short* hA = (unsigned short*)alloc(2ull * N_NODES * DIM);  // head h1
    unsigned short* hB = (unsigned short*)alloc(2ull * N_NODES * DIM);  // head h2/h3 ping-pong
    unsigned short* tA = (unsigned short*)alloc(2ull * N_NODES * DIM);  // tail t1
    unsigned short* tB = (unsigned short*)alloc(2ull * N_NODES * DIM);  // tail t2

    hipMemsetAsync(degi, 0, 4 * N_NODES, stream);
    k_degree<<<(N_EDGES + 255) / 256, 256, 0, stream>>>(esrc, degi);
    k_chunksum<<<NCHUNK, SCAN_B, 0, stream>>>(degi, bsum);
    k_scanb<<<1, 128, 0, stream>>>(bsum, NCHUNK);
    k_rowptr<<<NCHUNK, SCAN_B, 0, stream>>>(degi, bsum, rowptr, cnt, inv0, inv1, inv2);
    k_fill<<<(N_EDGES + 255) / 256, 256, 0, stream>>>(esrc, edst, cnt, col);
    k_pack<<<768, 256, 0, stream>>>(G1, G2, B1, B2, Wp);
    k_xcast<<<12500, 256, 0, stream>>>(x, xb);

    // F0: shared hop 0 — gathers S(x) once, emits head h1 (hA) AND tail t1 (tA)
    k_fused0<<<6250, 256, 0, stream>>>(xb, hA, tA, out, R, Wp,
                                       inv0, inv1, inv2, rowptr, degi, col);

    // hop 1: dual gather (tail tA->tB via GEMM, head hA->hB)
    k_hop<<<6250, 256, 0, stream>>>(tA, tB, hA, hB, xb, tA, hA, out,
                                    R + 128, Wp + 65536,
                                    inv0, inv1, inv2, rowptr, degi, col, 0);

    // hop 2 (final): head writes deg>5 rows, tail epilogue writes deg<=5 rows
    k_hop<<<6250, 256, 0, stream>>>(tB, (unsigned short*)0, hB, (unsigned short*)0,
                                    xb, tA, hA, out,
                                    R + 256, Wp + 131072,
                                    inv0, inv1, inv2, rowptr, degi, col, 1);
}